// Round 18
// baseline (348.084 us; speedup 1.0000x reference)
//
#include <hip/hip_runtime.h>
#include <hip/hip_bf16.h>

// Swin block on MI355X. Round 18: gemm_f8 BK 64->128 — r17 showed mlp2 is
// load-latency bound (conflicts 7.2M vs 18M gave identical time; MfmaUtil 26%,
// VALU 11%, BW 22%). Halve tile/barrier count, double per-tile compute and
// load-queue depth. Everything else identical to round 16/17.

typedef __bf16 bf16x8 __attribute__((ext_vector_type(8)));
typedef __bf16 bf16x4 __attribute__((ext_vector_type(4)));
typedef float  f32x4  __attribute__((ext_vector_type(4)));
typedef int    i32x4  __attribute__((ext_vector_type(4)));
typedef int    i32x2  __attribute__((ext_vector_type(2)));

#define GAS __attribute__((address_space(1)))
#define LAS __attribute__((address_space(3)))

#if __has_builtin(__builtin_amdgcn_cvt_pk_fp8_f32)
#define HAS_HW_FP8 1
#else
#define HAS_HW_FP8 0
#endif

__device__ __forceinline__ int div7u(int m) { return (m * 37) >> 8; }  // valid m<56

#if !HAS_HW_FP8
__device__ __forceinline__ unsigned fp8_enc1(float f) {
  f = fminf(fmaxf(f, -448.f), 448.f);
  unsigned u = __float_as_uint(f);
  unsigned s = u >> 31;
  int e8 = (int)((u >> 23) & 255) - 120;
  unsigned m32 = u & 0x7fffff;
  if (e8 <= 0) return s << 7;
  unsigned m = m32 >> 20;
  unsigned rem = m32 & 0xfffff;
  m += (rem > 0x80000u) || (rem == 0x80000u && (m & 1));
  if (m == 8) { m = 0; ++e8; }
  if (e8 > 15 || (e8 == 15 && m == 7)) { e8 = 15; m = 6; }
  return (s << 7) | ((unsigned)e8 << 3) | m;
}
#endif

template <bool HI>
__device__ __forceinline__ int fp8_pk2(float a, float b, int old) {
#if HAS_HW_FP8
  return __builtin_amdgcn_cvt_pk_fp8_f32(a, b, old, HI);
#else
  unsigned v = fp8_enc1(a) | (fp8_enc1(b) << 8);
  return HI ? (int)(((unsigned)old & 0xffffu) | (v << 16))
            : (int)(((unsigned)old & 0xffff0000u) | v);
#endif
}

// GELU via x*sigmoid(1.702x)
__device__ __forceinline__ float gelu_f(float v) {
  float s = __builtin_amdgcn_rcpf(1.f + __expf(-1.702f * v));
  return v * s;
}

// ---------------- weights cvt (bf16 + W3 fp8 x8) + bias expand ----------------
__global__ __launch_bounds__(256) void cvt_all_kernel(const float* __restrict__ s0,
                                                      const float* __restrict__ s1,
                                                      const float* __restrict__ s2,
                                                      const float* __restrict__ s3,
                                                      __bf16* __restrict__ d0,
                                                      __bf16* __restrict__ d1,
                                                      __bf16* __restrict__ d2,
                                                      unsigned char* __restrict__ d3,
                                                      const float* __restrict__ tbl,
                                                      float* __restrict__ be) {
  int i = blockIdx.x * 256 + threadIdx.x;
  if (i < 442368) { d0[i] = (__bf16)s0[i]; return; }
  i -= 442368;
  if (i < 147456) { d1[i] = (__bf16)s1[i]; return; }
  i -= 147456;
  if (i < 589824) { d2[i] = (__bf16)s2[i]; return; }
  i -= 589824;
  if (i < 294912) {                                  // W3 -> fp8, scaled x8
    int j = i << 1;
    int v = fp8_pk2<false>(s3[j] * 8.f, s3[j + 1] * 8.f, 0);
    ((unsigned short*)d3)[i] = (unsigned short)((unsigned)v & 0xffffu);
    return;
  }
  i -= 294912;
  if (i < 6 * 64 * 64) {
    int m = i & 63, n = (i >> 6) & 63, h = i >> 12;
    float v = 0.f;
    if (m < 49 && n < 49) {
      int in_ = div7u(n), jn = n - in_ * 7;
      int im  = div7u(m), jm = m - im * 7;
      v = tbl[((in_ - im + 6) * 13 + (jn - jm + 6)) * 6 + h];
    }
    be[i] = v;
  }
}

// ---------------- LayerNorm(channel) + transpose to token-major bf16 ----------------
template <typename TIN>
__global__ __launch_bounds__(256) void ln_t_kernel(const TIN* __restrict__ x,
                                                   const float* __restrict__ gw,
                                                   const float* __restrict__ gb,
                                                   __bf16* __restrict__ out) {
  __shared__ f32x4 ps[16][16], ps2[16][16];        // [sub][gq]
  __shared__ __align__(16) __bf16 tile[64][198];
  const int tid = threadIdx.x;
  const int lane = tid & 63, w = tid >> 6;
  const int gq = lane & 15;
  const int sub = (w << 2) + (lane >> 4);
  const int tok0 = blockIdx.x << 6;
  const int tokg4 = tok0 + (gq << 2);
  const unsigned b = (unsigned)tokg4 / 784u;
  const unsigned p = (unsigned)tokg4 - b * 784u;
  const TIN* xp = x + (size_t)b * 301056u + p;

  f32x4 vals[24];
  f32x4 s4 = {0.f, 0.f, 0.f, 0.f}, s24 = {0.f, 0.f, 0.f, 0.f};
  #pragma unroll
  for (int half = 0; half < 2; ++half)
    #pragma unroll
    for (int k = 0; k < 12; ++k) {
      int c = half * 192 + sub * 12 + k;
      f32x4 v;
      if constexpr (sizeof(TIN) == 4) {
        v = *(const f32x4*)(xp + (size_t)c * 784u);
      } else {
        bf16x4 t = *(const bf16x4*)(xp + (size_t)c * 784u);
        v = (f32x4){(float)t[0], (float)t[1], (float)t[2], (float)t[3]};
      }
      vals[half * 12 + k] = v;
      s4 += v;
      s24 += v * v;
    }
  ps[sub][gq] = s4;
  ps2[sub][gq] = s24;
  __syncthreads();
  f32x4 S = {0.f, 0.f, 0.f, 0.f}, S2 = {0.f, 0.f, 0.f, 0.f};
  #pragma unroll
  for (int i = 0; i < 16; ++i) { S += ps[i][gq]; S2 += ps2[i][gq]; }
  f32x4 mean = S * (1.f / 384.f);
  f32x4 var = (S2 - S * mean) * (1.f / 383.f);     // unbiased (ddof=1)
  f32x4 rstd;
  #pragma unroll
  for (int j = 0; j < 4; ++j) rstd[j] = rsqrtf(var[j] + 1e-5f);

  #pragma unroll
  for (int half = 0; half < 2; ++half) {
    if (half) __syncthreads();
    #pragma unroll
    for (int k = 0; k < 12; ++k) {
      int c = half * 192 + sub * 12 + k;
      float wgt = gw[c], bia = gb[c];
      f32x4 v = (vals[half * 12 + k] - mean) * rstd * wgt + bia;
      #pragma unroll
      for (int j = 0; j < 4; ++j)
        tile[(gq << 2) + j][sub * 12 + k] = (__bf16)v[j];
    }
    __syncthreads();
    #pragma unroll
    for (int it = 0; it < 6; ++it) {
      int idx = (it << 8) + tid;
      int row = idx / 24, colc = idx - row * 24;
      bf16x8 vv = *(const bf16x8*)(&tile[row][colc << 3]);
      *(bf16x8*)(out + (size_t)(tok0 + row) * 384 + half * 192 + (colc << 3)) = vv;
    }
  }
}

// ---------------- bf16 GEMM: C[m][tok] = A[m][:] . Bt[tok][:] ----------------
// 128x128, BK=64, single LDS buffer, reg-staged prefetch, 3 waves/EU hint.
// EPI 1: fast GELU + fp8 outT (mlp1; ldo bytes)
// EPI 3: swapped acc; fp32 resid -> bf16 out channel-major (proj)
// EPI 4: qkv mixed: m<768 -> fp8, m>=768 -> bf16; token row = 1536 B
template <int EPI>
__global__ __launch_bounds__(256, 3) void gemm_bt(const __bf16* __restrict__ A, int lda,
                                                  const __bf16* __restrict__ Bt, int ldb,
                                                  int K, int My,
                                                  void* __restrict__ outT, int ldo,
                                                  void* __restrict__ outR,
                                                  const float* __restrict__ resid) {
  __shared__ __align__(16) char smem[33792];
  const int tid = threadIdx.x;
  const int lane = tid & 63;
  const int w = tid >> 6;
  const int wr = w >> 1, wc = w & 1;
  const int c = lane & 15, g = lane >> 4;

  const int nwg = gridDim.x;
  const int orig = blockIdx.x;
  const int q = nwg >> 3, r = nwg & 7;
  const int xcd = orig & 7, ii = orig >> 3;
  const int wgid = (xcd < r ? xcd * (q + 1) : r * (q + 1) + (xcd - r) * q) + ii;
  const int bx = wgid / My;
  const int by = wgid - bx * My;
  const int m0 = by << 7;
  const int n0 = bx << 7;

  const __bf16* ap[4];
  const __bf16* bp[4];
  #pragma unroll
  for (int i = 0; i < 4; ++i) {
    int s = (i << 8) + tid;
    int row = s >> 3;
    int kk = ((s ^ row) & 7) << 3;
    ap[i] = A + (size_t)(m0 + row) * lda + kk;
    bp[i] = Bt + (size_t)(n0 + row) * ldb + kk;
  }

  i32x4 sA0, sA1, sA2, sA3, sB0, sB1, sB2, sB3;
  auto issue = [&](int k0) {
    sA0 = *(const i32x4*)(ap[0] + k0);
    sA1 = *(const i32x4*)(ap[1] + k0);
    sA2 = *(const i32x4*)(ap[2] + k0);
    sA3 = *(const i32x4*)(ap[3] + k0);
    sB0 = *(const i32x4*)(bp[0] + k0);
    sB1 = *(const i32x4*)(bp[1] + k0);
    sB2 = *(const i32x4*)(bp[2] + k0);
    sB3 = *(const i32x4*)(bp[3] + k0);
  };
  auto write_lds = [&]() {
    *(i32x4*)(smem +         (((0 << 8) + tid) << 4)) = sA0;
    *(i32x4*)(smem +         (((1 << 8) + tid) << 4)) = sA1;
    *(i32x4*)(smem +         (((2 << 8) + tid) << 4)) = sA2;
    *(i32x4*)(smem +         (((3 << 8) + tid) << 4)) = sA3;
    *(i32x4*)(smem + 16384 + (((0 << 8) + tid) << 4)) = sB0;
    *(i32x4*)(smem + 16384 + (((1 << 8) + tid) << 4)) = sB1;
    *(i32x4*)(smem + 16384 + (((2 << 8) + tid) << 4)) = sB2;
    *(i32x4*)(smem + 16384 + (((3 << 8) + tid) << 4)) = sB3;
  };

  f32x4 acc[4][4] = {};
  const int nt = K >> 6;

  issue(0);
  write_lds();
  asm volatile("s_waitcnt lgkmcnt(0)" ::: "memory");
  __builtin_amdgcn_s_barrier();
  __builtin_amdgcn_sched_barrier(0);

  for (int t = 0; t < nt; ++t) {
    if (t + 1 < nt) issue((t + 1) << 6);
    const char* smA = smem;
    const char* smB = smem + 16384;
    #pragma unroll
    for (int ks = 0; ks < 2; ++ks) {
      bf16x8 af[4], bfv[4];
      #pragma unroll
      for (int mi = 0; mi < 4; ++mi) {
        int r2 = (wr << 6) + (mi << 4) + c;
        af[mi] = *(const bf16x8*)(smA + (r2 << 7) + (((ks << 6) + (g << 4)) ^ ((r2 & 7) << 4)));
      }
      #pragma unroll
      for (int nj = 0; nj < 4; ++nj) {
        int r2 = (wc << 6) + (nj << 4) + c;
        bfv[nj] = *(const bf16x8*)(smB + (r2 << 7) + (((ks << 6) + (g << 4)) ^ ((r2 & 7) << 4)));
      }
      #pragma unroll
      for (int mi = 0; mi < 4; ++mi)
        #pragma unroll
        for (int nj = 0; nj < 4; ++nj) {
          if constexpr (EPI == 3)  // swapped: C rows = tokens
            acc[mi][nj] = __builtin_amdgcn_mfma_f32_16x16x32_bf16(bfv[nj], af[mi], acc[mi][nj], 0, 0, 0);
          else
            acc[mi][nj] = __builtin_amdgcn_mfma_f32_16x16x32_bf16(af[mi], bfv[nj], acc[mi][nj], 0, 0, 0);
        }
    }
    __builtin_amdgcn_s_barrier();
    if (t + 1 < nt) {
      write_lds();
      asm volatile("s_waitcnt lgkmcnt(0)" ::: "memory");
    }
    __builtin_amdgcn_s_barrier();
    __builtin_amdgcn_sched_barrier(0);
  }

  if constexpr (EPI != 3) {
    #pragma unroll
    for (int mi = 0; mi < 4; ++mi)
      #pragma unroll
      for (int nj = 0; nj < 4; ++nj) {
        f32x4 v = acc[mi][nj];
        if constexpr (EPI == 1) {
          #pragma unroll
          for (int r2 = 0; r2 < 4; ++r2) v[r2] = gelu_f(v[r2]);
        }
        bf16x4 pk = {(__bf16)v[0], (__bf16)v[1], (__bf16)v[2], (__bf16)v[3]};
        int nl = (wc << 6) + (nj << 4) + c;
        int ml = (wr << 6) + (mi << 4) + (g << 2);
        *(bf16x4*)(smem + nl * 264 + ml * 2) = pk;
      }
    __syncthreads();
    #pragma unroll
    for (int it = 0; it < 8; ++it) {
      int id = (it << 8) + tid;
      int n = id >> 4, mc = id & 15;
      bf16x8 v = *(const bf16x8*)(smem + n * 264 + (mc << 4));
      unsigned char* rowp = (unsigned char*)outT + (size_t)(n0 + n) * ldo;
      bool f8 = (EPI == 1) || (m0 < 768);
      if (f8) {
        int w0 = 0, w1 = 0;
        w0 = fp8_pk2<false>((float)v[0], (float)v[1], w0);
        w0 = fp8_pk2<true>((float)v[2], (float)v[3], w0);
        w1 = fp8_pk2<false>((float)v[4], (float)v[5], w1);
        w1 = fp8_pk2<true>((float)v[6], (float)v[7], w1);
        *(i32x2*)(rowp + m0 + (mc << 3)) = (i32x2){w0, w1};
      } else {
        *(bf16x8*)(rowp + 768 + ((m0 - 768) << 1) + (mc << 4)) = v;
      }
    }
  } else {
    // EPI 3: fp32 resid -> bf16 x2 channel-major
    #pragma unroll
    for (int nj = 0; nj < 4; ++nj) {
      int tokb = n0 + (wc << 6) + (nj << 4) + (g << 2);
      unsigned bb = (unsigned)tokb / 784u;
      unsigned pp = (unsigned)tokb - bb * 784u;
      size_t base2 = (size_t)bb * (384u * 784u) + pp;
      #pragma unroll
      for (int mi = 0; mi < 4; ++mi) {
        int o = m0 + (wr << 6) + (mi << 4) + c;
        size_t a2 = base2 + (size_t)o * 784u;
        f32x4 rv = *(const f32x4*)(resid + a2);
        f32x4 v = acc[mi][nj] + rv;
        bf16x4 pk = {(__bf16)v[0], (__bf16)v[1], (__bf16)v[2], (__bf16)v[3]};
        *(bf16x4*)((__bf16*)outR + a2) = pk;
      }
    }
  }
}

// ---------------- fp8 x fp8 GEMM (mlp2): out = h @ W3^T * 1/8 + x2 ----------------
// BK=128: 12 K-tiles, 32KB LDS (A 16K | B 16K), 16 loads in flight per stage.
// Layout: linear LDS dest; source/read granule XOR by row&15 (uniform pairs).
__global__ __launch_bounds__(256, 4) void gemm_f8(const unsigned char* __restrict__ A,
                                                  const unsigned char* __restrict__ Bt,
                                                  int My,
                                                  float* __restrict__ outR,
                                                  const __bf16* __restrict__ resid) {
  __shared__ __align__(16) char smem[32768];
  const int tid = threadIdx.x;
  const int lane = tid & 63;
  const int w = tid >> 6;
  const int wr = w >> 1, wc = w & 1;
  const int c = lane & 15, g = lane >> 4;

  const int nwg = gridDim.x;
  const int orig = blockIdx.x;
  const int q = nwg >> 3, r = nwg & 7;
  const int xcd = orig & 7, ii = orig >> 3;
  const int wgid = (xcd < r ? xcd * (q + 1) : r * (q + 1) + (xcd - r) * q) + ii;
  const int bx = wgid / My;
  const int by = wgid - bx * My;
  const int m0 = by << 7;                          // out-channel block
  const int n0 = bx << 7;                          // token block

  // staging: slot s=i*256+tid -> row=s>>4 (0..127), e=s&15 (8B granule);
  // global source granule pre-XOR'd by row&15; LDS dest linear s*8.
  const unsigned char* ap[8];
  const unsigned char* bp[8];
  #pragma unroll
  for (int i = 0; i < 8; ++i) {
    int s = (i << 8) + tid;
    int row = s >> 4;
    int e = s & 15;
    int src = ((e ^ row) & 15) << 3;
    ap[i] = A + (size_t)(m0 + row) * 1536 + src;
    bp[i] = Bt + (size_t)(n0 + row) * 1536 + src;
  }

  i32x2 ra[8], rb[8];
  auto issue = [&](int k0) {
    #pragma unroll
    for (int i = 0; i < 8; ++i) {
      ra[i] = *(const i32x2*)(ap[i] + k0);
      rb[i] = *(const i32x2*)(bp[i] + k0);
    }
  };
  auto write_lds = [&]() {
    #pragma unroll
    for (int i = 0; i < 8; ++i) {
      *(i32x2*)(smem +         ((((i << 8) + tid)) << 3)) = ra[i];
      *(i32x2*)(smem + 16384 + ((((i << 8) + tid)) << 3)) = rb[i];
    }
  };

  f32x4 acc[4][4] = {};

  issue(0);
  write_lds();
  asm volatile("s_waitcnt lgkmcnt(0)" ::: "memory");
  __builtin_amdgcn_s_barrier();
  __builtin_amdgcn_sched_barrier(0);

  for (int t = 0; t < 12; ++t) {                   // K = 1536 = 12 x 128
    if (t + 1 < 12) issue((t + 1) << 7);
    #pragma unroll
    for (int kk = 0; kk < 4; ++kk) {
      long af[4], bfv[4];
      const int f = (kk << 2) + g;                 // 0..15 k-granule
      #pragma unroll
      for (int mi = 0; mi < 4; ++mi) {
        int r2 = (wr << 6) + (mi << 4) + c;
        af[mi] = *(const long*)(smem + (r2 << 7) + (((f ^ r2) & 15) << 3));
      }
      #pragma unroll
      for (int nj = 0; nj < 4; ++nj) {
        int r2 = (wc << 6) + (nj << 4) + c;
        bfv[nj] = *(const long*)(smem + 16384 + (r2 << 7) + (((f ^ r2) & 15) << 3));
      }
      #pragma unroll
      for (int mi = 0; mi < 4; ++mi)
        #pragma unroll
        for (int nj = 0; nj < 4; ++nj)  // swapped: C rows = tokens
          acc[mi][nj] = __builtin_amdgcn_mfma_f32_16x16x32_fp8_fp8(bfv[nj], af[mi], acc[mi][nj], 0, 0, 0);
    }
    __builtin_amdgcn_s_barrier();
    if (t + 1 < 12) {
      write_lds();
      asm volatile("s_waitcnt lgkmcnt(0)" ::: "memory");
    }
    __builtin_amdgcn_s_barrier();
    __builtin_amdgcn_sched_barrier(0);
  }

  #pragma unroll
  for (int nj = 0; nj < 4; ++nj) {
    int tokb = n0 + (wc << 6) + (nj << 4) + (g << 2);
    unsigned bb = (unsigned)tokb / 784u;
    unsigned pp = (unsigned)tokb - bb * 784u;
    size_t base2 = (size_t)bb * (384u * 784u) + pp;
    #pragma unroll
    for (int mi = 0; mi < 4; ++mi) {
      int o = m0 + (wr << 6) + (mi << 4) + c;
      size_t a2 = base2 + (size_t)o * 784u;
      bf16x4 rv = *(const bf16x4*)(resid + a2);
      f32x4 v;
      #pragma unroll
      for (int j = 0; j < 4; ++j) v[j] = __builtin_fmaf(acc[mi][nj][j], 0.125f, (float)rv[j]);
      *(f32x4*)(outR + a2) = v;
    }
  }
}

// ---------------- windowed attention: fp8 QK^T, bf16 PV ----------------
// qkv row (1536 B): Q 384 fp8 | K 384 fp8 | V 384 bf16.
__global__ __launch_bounds__(256, 2) void attn_kernel(const unsigned char* __restrict__ qkv8,
                                                      const float* __restrict__ be,
                                                      __bf16* __restrict__ outt) {
  __shared__ __align__(16) char smem_all[4][16384];
  const int tid = threadIdx.x;
  const int lane = tid & 63;
  const int w = tid >> 6;
  char* sm = (char*)smem_all[w];
  const int pair = blockIdx.x * 4 + w;               // 6144 pairs
  const int h = pair % 6;
  const int wg = pair / 6;
  const int b = wg >> 4;
  const int wi = wg & 15;
  const int wh = wi >> 2, wwi = wi & 3;
  const int cc = lane & 15, g = lane >> 4;

  // ---- stage K (0..4K) and Q (4..8K): 64 rows x 64B fp8, 16B-granule XOR ----
  {
    int rsub = lane >> 2;                            // 0..15
    int G = lane & 3;
    #pragma unroll
    for (int it = 0; it < 4; ++it) {
      int r = it * 16 + rsub;
      int m = r < 49 ? r : 48;
      int im = div7u(m), jm = m - im * 7;
      int sh = wh * 7 + im + 3; if (sh >= 28) sh -= 28;
      int sw = wwi * 7 + jm + 3; if (sw >= 28) sw -= 28;
      size_t trow = (size_t)(b * 784 + sh * 28 + sw) * 1536;
      int srcG = (G ^ (r & 3)) << 4;
      __builtin_amdgcn_global_load_lds((const GAS void*)(qkv8 + trow + 384 + h * 64 + srcG),
                                       (LAS void*)(sm + it * 1024), 16, 0, 0);         // K
      __builtin_amdgcn_global_load_lds((const GAS void*)(qkv8 + trow + h * 64 + srcG),
                                       (LAS void*)(sm + 4096 + it * 1024), 16, 0, 0);  // Q
    }
  }
  asm volatile("s_waitcnt vmcnt(0)" ::: "memory");
  __syncthreads();

  // ---- S^T = K @ Q^T (fp8), rows m = keys, cols n = queries ----
  f32x4 sacc[4][4] = {};
  #pragma unroll
  for (int ks = 0; ks < 2; ++ks) {
    long kf[4], qf[4];
    const int e = (ks << 2) + g;                     // 0..7 (8-elem k-chunk)
    #pragma unroll
    for (int mi = 0; mi < 4; ++mi) {
      int r = (mi << 4) + cc;
      int addr = (r << 6) + ((((e >> 1) ^ (r & 3)) << 4)) + ((e & 1) << 3);
      kf[mi] = *(const long*)(sm + addr);
    }
    #pragma unroll
    for (int nj = 0; nj < 4; ++nj) {
      int r = (nj << 4) + cc;
      int addr = (r << 6) + ((((e >> 1) ^ (r & 3)) << 4)) + ((e & 1) << 3);
      qf[nj] = *(const long*)(sm + 4096 + addr);
    }
    #pragma unroll
    for (int mi = 0; mi < 4; ++mi)
      #pragma unroll
      for (int nj = 0; nj < 4; ++nj)
        sacc[mi][nj] = __builtin_amdgcn_mfma_f32_16x16x32_fp8_fp8(kf[mi], qf[nj], sacc[mi][nj], 0, 0, 0);
  }
  __syncthreads();

  int r9m[4][4];
  #pragma unroll
  for (int mi = 0; mi < 4; ++mi)
    #pragma unroll
    for (int rr = 0; rr < 4; ++rr) {
      int m = (mi << 4) + (g << 2) + rr; if (m > 48) m = 48;
      int im = div7u(m), jm = m - im * 7;
      int sh = wh * 7 + im, sw = wwi * 7 + jm;
      r9m[mi][rr] = ((sh < 21) ? 0 : (sh < 25 ? 1 : 2)) * 3 + ((sw < 21) ? 0 : (sw < 25 ? 1 : 2));
    }

  #pragma unroll
  for (int nj = 0; nj < 4; ++nj) {
    int n = (nj << 4) + cc;
    int ncl = n > 48 ? 48 : n;
    int in_ = div7u(ncl), jn = ncl - in_ * 7;
    int shn = wh * 7 + in_, swn = wwi * 7 + jn;
    int r9n = ((shn < 21) ? 0 : (shn < 25 ? 1 : 2)) * 3 + ((swn < 21) ? 0 : (swn < 25 ? 1 : 2));
    float mx = -1e30f;
    #pragma unroll
    for (int mi = 0; mi < 4; ++mi) {
      f32x4 bia = *(const f32x4*)(be + (((h << 6) + n) << 6) + (mi << 4) + (g << 2));
      #pragma unroll
      for (int rr = 0; rr < 4; ++rr) {
        int m = (mi << 4) + (g << 2) + rr;
        float t = (m < 49)
            ? sacc[mi][nj][rr] * 0.125f + bia[rr] + ((r9m[mi][rr] == r9n) ? 0.f : -100.f)
            : -1e30f;
        sacc[mi][nj][rr] = t;
        mx = fmaxf(mx, t);
      }
    }
    mx = fmaxf(mx, __shfl_xor(mx, 16, 64));
    mx = fmaxf(mx, __shfl_xor(mx, 32, 64));
    float sum = 0.f;
    #pragma unroll
    for (int mi = 0; mi < 4; ++mi)
      #pragma unroll
      for (int rr = 0; rr < 4; ++rr) {
        float e = __expf(sacc[mi][nj][rr] - mx);
        sacc[mi][nj][rr] = e;
        sum += e;
      }
    sum += __shfl_xor(sum, 16, 64);
    sum += __shfl_xor(sum, 32, 64);
    float inv = __builtin_amdgcn_rcpf(sum);
    #pragma unroll
    for (int mi = 0; mi < 4; ++mi) {
      bf16x4 pk = {(__bf16)(sacc[mi][nj][0] * inv), (__bf16)(sacc[mi][nj][1] * inv),
                   (__bf16)(sacc[mi][nj][2] * inv), (__bf16)(sacc[mi][nj][3] * inv)};
      *(bf16x4*)(sm + 8192 + (n << 7) + (((mi << 5) + (g << 3)) ^ ((n & 7) << 4))) = pk;
    }
  }

  // ---- stage V^T (bf16) -> sm[0..8K): VT[d][m] ----
  {
    int ml = lane & 15, dq = lane >> 4;
    #pragma unroll
    for (int it = 0; it < 4; ++it) {
      int m = (it << 4) + ml;
      int mc_ = m > 48 ? 48 : m;
      int im = div7u(mc_), jm = mc_ - im * 7;
      int sh = wh * 7 + im + 3; if (sh >= 28) sh -= 28;
      int sw = wwi * 7 + jm + 3; if (sw >= 28) sw -= 28;
      const __bf16* gv = (const __bf16*)(qkv8 + (size_t)(b * 784 + sh * 28 + sw) * 1536 + 768) + h * 64;
      #pragma unroll
      for (int hd = 0; hd < 2; ++hd) {
        int dbase = (hd << 5) + (dq << 3);
        bf16x8 v = *(const bf16x8*)(gv + dbase);
        #pragma unroll
        for (int j = 0; j < 8; ++j) {
          int d = dbase + j;
          *(__bf16*)(sm + (d << 7) + ((((m >> 3) ^ (d & 7)) << 4) + ((m & 7) << 1))) = v[j];
        }
      }
    }
  }
  __syncthreads();

  f32x4 oacc[4][4] = {};
  #pragma unroll
  for (int ks = 0; ks < 2; ++ks) {
    bf16x8 pf[4], vf[4];
    #pragma unroll
    for (int ni = 0; ni < 4; ++ni) {
      int n = (ni << 4) + cc;
      pf[ni] = *(const bf16x8*)(sm + 8192 + (n << 7) + (((ks << 6) + (g << 4)) ^ ((n & 7) << 4)));
    }
    #pragma unroll
    for (int dj = 0; dj < 4; ++dj) {
      int d = (dj << 4) + cc;
      vf[dj] = *(const bf16x8*)(sm + (d << 7) + ((((ks << 2) + g) ^ (d & 7)) << 4));
    }
    #pragma unroll
    for (int ni = 0; ni < 4; ++ni)
      #pragma unroll
      for (int dj = 0; dj < 4; ++dj)
        oacc[ni][dj] = __builtin_amdgcn_mfma_f32_16x16x32_bf16(pf[ni], vf[dj], oacc[ni][dj], 0, 0, 0);
  }

  #pragma unroll
  for (int ni = 0; ni < 4; ++ni)
    #pragma unroll
    for (int rr = 0; rr < 4; ++rr) {
      int n = (ni << 4) + (g << 2) + rr;
      if (n < 49) {
        int im = div7u(n), jn = n - im * 7;
        int sh = wh * 7 + im + 3; if (sh >= 28) sh -= 28;
        int sw = wwi * 7 + jn + 3; if (sw >= 28) sw -= 28;
        __bf16* op = outt + (size_t)(b * 784 + sh * 28 + sw) * 384 + h * 64;
        #pragma unroll
        for (int dj = 0; dj < 4; ++dj)
          op[(dj << 4) + cc] = (__bf16)oacc[ni][dj][rr];
      }
    }
}

// ---------------- host launcher ----------------
extern "C" void kernel_launch(void* const* d_in, const int* in_sizes, int n_in,
                              void* d_out, int out_size, void* d_ws, size_t ws_size,
                              hipStream_t stream) {
  (void)in_sizes; (void)n_in; (void)out_size; (void)ws_size;
  const float* x     = (const float*)d_in[0];
  const float* n1w   = (const float*)d_in[1];
  const float* n1b   = (const float*)d_in[2];
  const float* qkvw  = (const float*)d_in[3];
  const float* tbl   = (const float*)d_in[4];
  const float* projw = (const float*)d_in[5];
  const float* n2w   = (const float*)d_in[6];
  const float* n2b   = (const float*)d_in[7];
  const float* w1    = (const float*)d_in[8];
  const float* w3    = (const float*)d_in[9];
  float* out = (float*)d_out;

  char* ws = (char*)d_ws;
  __bf16* bufA = (__bf16*)ws;                               // 38,535,168 B
  unsigned char* h8 = (unsigned char*)(ws + 38535168);      // 77,070,336 B (qkv8 / h fp8)
  __bf16* x2b = (__bf16*)(ws + 38535168 + 77070336);        // 38,535,168 B (x2 bf16)
  float*  be   = (float*)(ws + 154140672);                  // 98,304 B
  __bf16* wq   = (__bf16*)(ws + 154238976);
  __bf16* wp   = wq + 442368;
  __bf16* wm1  = wp + 147456;
  unsigned char* w3f8 = (unsigned char*)(wm1 + 589824);     // 589,824 B fp8

  cvt_all_kernel<<<5856, 256, 0, stream>>>(qkvw, projw, w1, w3, wq, wp, wm1, w3f8, tbl, be);

  // LN1(x fp32) -> xn_t (bufA)
  ln_t_kernel<float><<<784, 256, 0, stream>>>(x, n1w, n1b, bufA);
  // qkv -> mixed-precision qkv8 [tok][1536B]: Q,K fp8 + V bf16
  gemm_bt<4><<<392 * 9, 256, 0, stream>>>(wq, 384, bufA, 384, 384, 9,
                                          (void*)h8, 1536, nullptr, nullptr);
  // attention -> attn_out_t (bufA)
  attn_kernel<<<1536, 256, 0, stream>>>(h8, be, bufA);
  // proj: attn_out @ Wp + x -> x2 bf16 channel-major (x2b)
  gemm_bt<3><<<392 * 3, 256, 0, stream>>>(wp, 384, bufA, 384, 384, 3,
                                          nullptr, 0, (void*)x2b, x);
  // LN2(x2 bf16) -> xn2_t (bufA)
  ln_t_kernel<__bf16><<<784, 256, 0, stream>>>(x2b, n2w, n2b, bufA);
  // mlp1: xn2 @ W1 -> gelu -> h fp8 (h8)
  gemm_bt<1><<<392 * 12, 256, 0, stream>>>(wm1, 384, bufA, 384, 384, 12,
                                           (void*)h8, 1536, nullptr, nullptr);
  // mlp2 (fp8 x fp8): h @ W3^T /8 + x2 -> final fp32 out
  gemm_f8<<<392 * 3, 256, 0, stream>>>(w3f8, h8, 3, out, x2b);
}

// Round 19
// 333.258 us; speedup vs baseline: 1.0445x; 1.0445x over previous
//
#include <hip/hip_runtime.h>
#include <hip/hip_bf16.h>

// Swin block on MI355X. Round 19: revert gemm_f8 to the round-16 version
// (BK=64, 4 ptrs, 16KB LDS — r18's BK=128 spilled: 8+8 ptrs + 16 staging regs
// under the (256,4) 128-VGPR cap -> scratch, FETCH 67->80MB, 87->100us).
// This restores the best-known 335us configuration.

typedef __bf16 bf16x8 __attribute__((ext_vector_type(8)));
typedef __bf16 bf16x4 __attribute__((ext_vector_type(4)));
typedef float  f32x4  __attribute__((ext_vector_type(4)));
typedef int    i32x4  __attribute__((ext_vector_type(4)));
typedef int    i32x2  __attribute__((ext_vector_type(2)));

#define GAS __attribute__((address_space(1)))
#define LAS __attribute__((address_space(3)))

#if __has_builtin(__builtin_amdgcn_cvt_pk_fp8_f32)
#define HAS_HW_FP8 1
#else
#define HAS_HW_FP8 0
#endif

__device__ __forceinline__ int div7u(int m) { return (m * 37) >> 8; }  // valid m<56

#if !HAS_HW_FP8
__device__ __forceinline__ unsigned fp8_enc1(float f) {
  f = fminf(fmaxf(f, -448.f), 448.f);
  unsigned u = __float_as_uint(f);
  unsigned s = u >> 31;
  int e8 = (int)((u >> 23) & 255) - 120;
  unsigned m32 = u & 0x7fffff;
  if (e8 <= 0) return s << 7;
  unsigned m = m32 >> 20;
  unsigned rem = m32 & 0xfffff;
  m += (rem > 0x80000u) || (rem == 0x80000u && (m & 1));
  if (m == 8) { m = 0; ++e8; }
  if (e8 > 15 || (e8 == 15 && m == 7)) { e8 = 15; m = 6; }
  return (s << 7) | ((unsigned)e8 << 3) | m;
}
#endif

template <bool HI>
__device__ __forceinline__ int fp8_pk2(float a, float b, int old) {
#if HAS_HW_FP8
  return __builtin_amdgcn_cvt_pk_fp8_f32(a, b, old, HI);
#else
  unsigned v = fp8_enc1(a) | (fp8_enc1(b) << 8);
  return HI ? (int)(((unsigned)old & 0xffffu) | (v << 16))
            : (int)(((unsigned)old & 0xffff0000u) | v);
#endif
}

// GELU via x*sigmoid(1.702x)
__device__ __forceinline__ float gelu_f(float v) {
  float s = __builtin_amdgcn_rcpf(1.f + __expf(-1.702f * v));
  return v * s;
}

// ---------------- weights cvt (bf16 + W3 fp8 x8) + bias expand ----------------
__global__ __launch_bounds__(256) void cvt_all_kernel(const float* __restrict__ s0,
                                                      const float* __restrict__ s1,
                                                      const float* __restrict__ s2,
                                                      const float* __restrict__ s3,
                                                      __bf16* __restrict__ d0,
                                                      __bf16* __restrict__ d1,
                                                      __bf16* __restrict__ d2,
                                                      unsigned char* __restrict__ d3,
                                                      const float* __restrict__ tbl,
                                                      float* __restrict__ be) {
  int i = blockIdx.x * 256 + threadIdx.x;
  if (i < 442368) { d0[i] = (__bf16)s0[i]; return; }
  i -= 442368;
  if (i < 147456) { d1[i] = (__bf16)s1[i]; return; }
  i -= 147456;
  if (i < 589824) { d2[i] = (__bf16)s2[i]; return; }
  i -= 589824;
  if (i < 294912) {                                  // W3 -> fp8, scaled x8
    int j = i << 1;
    int v = fp8_pk2<false>(s3[j] * 8.f, s3[j + 1] * 8.f, 0);
    ((unsigned short*)d3)[i] = (unsigned short)((unsigned)v & 0xffffu);
    return;
  }
  i -= 294912;
  if (i < 6 * 64 * 64) {
    int m = i & 63, n = (i >> 6) & 63, h = i >> 12;
    float v = 0.f;
    if (m < 49 && n < 49) {
      int in_ = div7u(n), jn = n - in_ * 7;
      int im  = div7u(m), jm = m - im * 7;
      v = tbl[((in_ - im + 6) * 13 + (jn - jm + 6)) * 6 + h];
    }
    be[i] = v;
  }
}

// ---------------- LayerNorm(channel) + transpose to token-major bf16 ----------------
template <typename TIN>
__global__ __launch_bounds__(256) void ln_t_kernel(const TIN* __restrict__ x,
                                                   const float* __restrict__ gw,
                                                   const float* __restrict__ gb,
                                                   __bf16* __restrict__ out) {
  __shared__ f32x4 ps[16][16], ps2[16][16];        // [sub][gq]
  __shared__ __align__(16) __bf16 tile[64][198];
  const int tid = threadIdx.x;
  const int lane = tid & 63, w = tid >> 6;
  const int gq = lane & 15;
  const int sub = (w << 2) + (lane >> 4);
  const int tok0 = blockIdx.x << 6;
  const int tokg4 = tok0 + (gq << 2);
  const unsigned b = (unsigned)tokg4 / 784u;
  const unsigned p = (unsigned)tokg4 - b * 784u;
  const TIN* xp = x + (size_t)b * 301056u + p;

  f32x4 vals[24];
  f32x4 s4 = {0.f, 0.f, 0.f, 0.f}, s24 = {0.f, 0.f, 0.f, 0.f};
  #pragma unroll
  for (int half = 0; half < 2; ++half)
    #pragma unroll
    for (int k = 0; k < 12; ++k) {
      int c = half * 192 + sub * 12 + k;
      f32x4 v;
      if constexpr (sizeof(TIN) == 4) {
        v = *(const f32x4*)(xp + (size_t)c * 784u);
      } else {
        bf16x4 t = *(const bf16x4*)(xp + (size_t)c * 784u);
        v = (f32x4){(float)t[0], (float)t[1], (float)t[2], (float)t[3]};
      }
      vals[half * 12 + k] = v;
      s4 += v;
      s24 += v * v;
    }
  ps[sub][gq] = s4;
  ps2[sub][gq] = s24;
  __syncthreads();
  f32x4 S = {0.f, 0.f, 0.f, 0.f}, S2 = {0.f, 0.f, 0.f, 0.f};
  #pragma unroll
  for (int i = 0; i < 16; ++i) { S += ps[i][gq]; S2 += ps2[i][gq]; }
  f32x4 mean = S * (1.f / 384.f);
  f32x4 var = (S2 - S * mean) * (1.f / 383.f);     // unbiased (ddof=1)
  f32x4 rstd;
  #pragma unroll
  for (int j = 0; j < 4; ++j) rstd[j] = rsqrtf(var[j] + 1e-5f);

  #pragma unroll
  for (int half = 0; half < 2; ++half) {
    if (half) __syncthreads();
    #pragma unroll
    for (int k = 0; k < 12; ++k) {
      int c = half * 192 + sub * 12 + k;
      float wgt = gw[c], bia = gb[c];
      f32x4 v = (vals[half * 12 + k] - mean) * rstd * wgt + bia;
      #pragma unroll
      for (int j = 0; j < 4; ++j)
        tile[(gq << 2) + j][sub * 12 + k] = (__bf16)v[j];
    }
    __syncthreads();
    #pragma unroll
    for (int it = 0; it < 6; ++it) {
      int idx = (it << 8) + tid;
      int row = idx / 24, colc = idx - row * 24;
      bf16x8 vv = *(const bf16x8*)(&tile[row][colc << 3]);
      *(bf16x8*)(out + (size_t)(tok0 + row) * 384 + half * 192 + (colc << 3)) = vv;
    }
  }
}

// ---------------- bf16 GEMM: C[m][tok] = A[m][:] . Bt[tok][:] ----------------
// 128x128, BK=64, single LDS buffer, reg-staged prefetch, 3 waves/EU hint.
// EPI 1: fast GELU + fp8 outT (mlp1; ldo bytes)
// EPI 3: swapped acc; fp32 resid -> bf16 out channel-major (proj)
// EPI 4: qkv mixed: m<768 -> fp8, m>=768 -> bf16; token row = 1536 B
template <int EPI>
__global__ __launch_bounds__(256, 3) void gemm_bt(const __bf16* __restrict__ A, int lda,
                                                  const __bf16* __restrict__ Bt, int ldb,
                                                  int K, int My,
                                                  void* __restrict__ outT, int ldo,
                                                  void* __restrict__ outR,
                                                  const float* __restrict__ resid) {
  __shared__ __align__(16) char smem[33792];
  const int tid = threadIdx.x;
  const int lane = tid & 63;
  const int w = tid >> 6;
  const int wr = w >> 1, wc = w & 1;
  const int c = lane & 15, g = lane >> 4;

  const int nwg = gridDim.x;
  const int orig = blockIdx.x;
  const int q = nwg >> 3, r = nwg & 7;
  const int xcd = orig & 7, ii = orig >> 3;
  const int wgid = (xcd < r ? xcd * (q + 1) : r * (q + 1) + (xcd - r) * q) + ii;
  const int bx = wgid / My;
  const int by = wgid - bx * My;
  const int m0 = by << 7;
  const int n0 = bx << 7;

  const __bf16* ap[4];
  const __bf16* bp[4];
  #pragma unroll
  for (int i = 0; i < 4; ++i) {
    int s = (i << 8) + tid;
    int row = s >> 3;
    int kk = ((s ^ row) & 7) << 3;
    ap[i] = A + (size_t)(m0 + row) * lda + kk;
    bp[i] = Bt + (size_t)(n0 + row) * ldb + kk;
  }

  i32x4 sA0, sA1, sA2, sA3, sB0, sB1, sB2, sB3;
  auto issue = [&](int k0) {
    sA0 = *(const i32x4*)(ap[0] + k0);
    sA1 = *(const i32x4*)(ap[1] + k0);
    sA2 = *(const i32x4*)(ap[2] + k0);
    sA3 = *(const i32x4*)(ap[3] + k0);
    sB0 = *(const i32x4*)(bp[0] + k0);
    sB1 = *(const i32x4*)(bp[1] + k0);
    sB2 = *(const i32x4*)(bp[2] + k0);
    sB3 = *(const i32x4*)(bp[3] + k0);
  };
  auto write_lds = [&]() {
    *(i32x4*)(smem +         (((0 << 8) + tid) << 4)) = sA0;
    *(i32x4*)(smem +         (((1 << 8) + tid) << 4)) = sA1;
    *(i32x4*)(smem +         (((2 << 8) + tid) << 4)) = sA2;
    *(i32x4*)(smem +         (((3 << 8) + tid) << 4)) = sA3;
    *(i32x4*)(smem + 16384 + (((0 << 8) + tid) << 4)) = sB0;
    *(i32x4*)(smem + 16384 + (((1 << 8) + tid) << 4)) = sB1;
    *(i32x4*)(smem + 16384 + (((2 << 8) + tid) << 4)) = sB2;
    *(i32x4*)(smem + 16384 + (((3 << 8) + tid) << 4)) = sB3;
  };

  f32x4 acc[4][4] = {};
  const int nt = K >> 6;

  issue(0);
  write_lds();
  asm volatile("s_waitcnt lgkmcnt(0)" ::: "memory");
  __builtin_amdgcn_s_barrier();
  __builtin_amdgcn_sched_barrier(0);

  for (int t = 0; t < nt; ++t) {
    if (t + 1 < nt) issue((t + 1) << 6);
    const char* smA = smem;
    const char* smB = smem + 16384;
    #pragma unroll
    for (int ks = 0; ks < 2; ++ks) {
      bf16x8 af[4], bfv[4];
      #pragma unroll
      for (int mi = 0; mi < 4; ++mi) {
        int r2 = (wr << 6) + (mi << 4) + c;
        af[mi] = *(const bf16x8*)(smA + (r2 << 7) + (((ks << 6) + (g << 4)) ^ ((r2 & 7) << 4)));
      }
      #pragma unroll
      for (int nj = 0; nj < 4; ++nj) {
        int r2 = (wc << 6) + (nj << 4) + c;
        bfv[nj] = *(const bf16x8*)(smB + (r2 << 7) + (((ks << 6) + (g << 4)) ^ ((r2 & 7) << 4)));
      }
      #pragma unroll
      for (int mi = 0; mi < 4; ++mi)
        #pragma unroll
        for (int nj = 0; nj < 4; ++nj) {
          if constexpr (EPI == 3)  // swapped: C rows = tokens
            acc[mi][nj] = __builtin_amdgcn_mfma_f32_16x16x32_bf16(bfv[nj], af[mi], acc[mi][nj], 0, 0, 0);
          else
            acc[mi][nj] = __builtin_amdgcn_mfma_f32_16x16x32_bf16(af[mi], bfv[nj], acc[mi][nj], 0, 0, 0);
        }
    }
    __builtin_amdgcn_s_barrier();
    if (t + 1 < nt) {
      write_lds();
      asm volatile("s_waitcnt lgkmcnt(0)" ::: "memory");
    }
    __builtin_amdgcn_s_barrier();
    __builtin_amdgcn_sched_barrier(0);
  }

  if constexpr (EPI != 3) {
    #pragma unroll
    for (int mi = 0; mi < 4; ++mi)
      #pragma unroll
      for (int nj = 0; nj < 4; ++nj) {
        f32x4 v = acc[mi][nj];
        if constexpr (EPI == 1) {
          #pragma unroll
          for (int r2 = 0; r2 < 4; ++r2) v[r2] = gelu_f(v[r2]);
        }
        bf16x4 pk = {(__bf16)v[0], (__bf16)v[1], (__bf16)v[2], (__bf16)v[3]};
        int nl = (wc << 6) + (nj << 4) + c;
        int ml = (wr << 6) + (mi << 4) + (g << 2);
        *(bf16x4*)(smem + nl * 264 + ml * 2) = pk;
      }
    __syncthreads();
    #pragma unroll
    for (int it = 0; it < 8; ++it) {
      int id = (it << 8) + tid;
      int n = id >> 4, mc = id & 15;
      bf16x8 v = *(const bf16x8*)(smem + n * 264 + (mc << 4));
      unsigned char* rowp = (unsigned char*)outT + (size_t)(n0 + n) * ldo;
      bool f8 = (EPI == 1) || (m0 < 768);
      if (f8) {
        int w0 = 0, w1 = 0;
        w0 = fp8_pk2<false>((float)v[0], (float)v[1], w0);
        w0 = fp8_pk2<true>((float)v[2], (float)v[3], w0);
        w1 = fp8_pk2<false>((float)v[4], (float)v[5], w1);
        w1 = fp8_pk2<true>((float)v[6], (float)v[7], w1);
        *(i32x2*)(rowp + m0 + (mc << 3)) = (i32x2){w0, w1};
      } else {
        *(bf16x8*)(rowp + 768 + ((m0 - 768) << 1) + (mc << 4)) = v;
      }
    }
  } else {
    // EPI 3: fp32 resid -> bf16 x2 channel-major
    #pragma unroll
    for (int nj = 0; nj < 4; ++nj) {
      int tokb = n0 + (wc << 6) + (nj << 4) + (g << 2);
      unsigned bb = (unsigned)tokb / 784u;
      unsigned pp = (unsigned)tokb - bb * 784u;
      size_t base2 = (size_t)bb * (384u * 784u) + pp;
      #pragma unroll
      for (int mi = 0; mi < 4; ++mi) {
        int o = m0 + (wr << 6) + (mi << 4) + c;
        size_t a2 = base2 + (size_t)o * 784u;
        f32x4 rv = *(const f32x4*)(resid + a2);
        f32x4 v = acc[mi][nj] + rv;
        bf16x4 pk = {(__bf16)v[0], (__bf16)v[1], (__bf16)v[2], (__bf16)v[3]};
        *(bf16x4*)((__bf16*)outR + a2) = pk;
      }
    }
  }
}

// ---------------- fp8 x fp8 GEMM (mlp2): out = h @ W3^T * 1/8 + x2 ----------------
__global__ __launch_bounds__(256, 4) void gemm_f8(const unsigned char* __restrict__ A,
                                                  const unsigned char* __restrict__ Bt,
                                                  int My,
                                                  float* __restrict__ outR,
                                                  const __bf16* __restrict__ resid) {
  __shared__ __align__(16) char smem[16384];       // A 8K | B 8K
  const int tid = threadIdx.x;
  const int lane = tid & 63;
  const int w = tid >> 6;
  const int wr = w >> 1, wc = w & 1;
  const int c = lane & 15, g = lane >> 4;

  const int nwg = gridDim.x;
  const int orig = blockIdx.x;
  const int q = nwg >> 3, r = nwg & 7;
  const int xcd = orig & 7, ii = orig >> 3;
  const int wgid = (xcd < r ? xcd * (q + 1) : r * (q + 1) + (xcd - r) * q) + ii;
  const int bx = wgid / My;
  const int by = wgid - bx * My;
  const int m0 = by << 7;
  const int n0 = bx << 7;

  const unsigned char* ap[4];
  const unsigned char* bp[4];
  #pragma unroll
  for (int i = 0; i < 4; ++i) {
    int s = (i << 8) + tid;
    int row = s >> 3;
    int off = ((s ^ row) & 7) << 3;
    ap[i] = A + (size_t)(m0 + row) * 1536 + off;
    bp[i] = Bt + (size_t)(n0 + row) * 1536 + off;
  }

  i32x2 a0, a1, a2r, a3, b0, b1, b2, b3;
  auto issue = [&](int k0) {
    a0 = *(const i32x2*)(ap[0] + k0); b0 = *(const i32x2*)(bp[0] + k0);
    a1 = *(const i32x2*)(ap[1] + k0); b1 = *(const i32x2*)(bp[1] + k0);
    a2r = *(const i32x2*)(ap[2] + k0); b2 = *(const i32x2*)(bp[2] + k0);
    a3 = *(const i32x2*)(ap[3] + k0); b3 = *(const i32x2*)(bp[3] + k0);
  };
  auto write_lds = [&]() {
    *(i32x2*)(smem +        (((0 << 8) + tid) << 3)) = a0;
    *(i32x2*)(smem +        (((1 << 8) + tid) << 3)) = a1;
    *(i32x2*)(smem +        (((2 << 8) + tid) << 3)) = a2r;
    *(i32x2*)(smem +        (((3 << 8) + tid) << 3)) = a3;
    *(i32x2*)(smem + 8192 + (((0 << 8) + tid) << 3)) = b0;
    *(i32x2*)(smem + 8192 + (((1 << 8) + tid) << 3)) = b1;
    *(i32x2*)(smem + 8192 + (((2 << 8) + tid) << 3)) = b2;
    *(i32x2*)(smem + 8192 + (((3 << 8) + tid) << 3)) = b3;
  };

  f32x4 acc[4][4] = {};

  issue(0);
  write_lds();
  asm volatile("s_waitcnt lgkmcnt(0)" ::: "memory");
  __builtin_amdgcn_s_barrier();
  __builtin_amdgcn_sched_barrier(0);

  for (int t = 0; t < 24; ++t) {                   // K = 1536 = 24 x 64
    if (t + 1 < 24) issue((t + 1) << 6);
    #pragma unroll
    for (int ks = 0; ks < 2; ++ks) {
      long af[4], bfv[4];
      #pragma unroll
      for (int mi = 0; mi < 4; ++mi) {
        int r2 = (wr << 6) + (mi << 4) + c;
        af[mi] = *(const long*)(smem + (r2 << 6) + ((((ks << 2) + g) ^ (r2 & 7)) << 3));
      }
      #pragma unroll
      for (int nj = 0; nj < 4; ++nj) {
        int r2 = (wc << 6) + (nj << 4) + c;
        bfv[nj] = *(const long*)(smem + 8192 + (r2 << 6) + ((((ks << 2) + g) ^ (r2 & 7)) << 3));
      }
      #pragma unroll
      for (int mi = 0; mi < 4; ++mi)
        #pragma unroll
        for (int nj = 0; nj < 4; ++nj)  // swapped: C rows = tokens
          acc[mi][nj] = __builtin_amdgcn_mfma_f32_16x16x32_fp8_fp8(bfv[nj], af[mi], acc[mi][nj], 0, 0, 0);
    }
    __builtin_amdgcn_s_barrier();
    if (t + 1 < 24) {
      write_lds();
      asm volatile("s_waitcnt lgkmcnt(0)" ::: "memory");
    }
    __builtin_amdgcn_s_barrier();
    __builtin_amdgcn_sched_barrier(0);
  }

  #pragma unroll
  for (int nj = 0; nj < 4; ++nj) {
    int tokb = n0 + (wc << 6) + (nj << 4) + (g << 2);
    unsigned bb = (unsigned)tokb / 784u;
    unsigned pp = (unsigned)tokb - bb * 784u;
    size_t base2 = (size_t)bb * (384u * 784u) + pp;
    #pragma unroll
    for (int mi = 0; mi < 4; ++mi) {
      int o = m0 + (wr << 6) + (mi << 4) + c;
      size_t a2 = base2 + (size_t)o * 784u;
      bf16x4 rv = *(const bf16x4*)(resid + a2);
      f32x4 v;
      #pragma unroll
      for (int j = 0; j < 4; ++j) v[j] = __builtin_fmaf(acc[mi][nj][j], 0.125f, (float)rv[j]);
      *(f32x4*)(outR + a2) = v;
    }
  }
}

// ---------------- windowed attention: fp8 QK^T, bf16 PV ----------------
// qkv row (1536 B): Q 384 fp8 | K 384 fp8 | V 384 bf16.
__global__ __launch_bounds__(256, 2) void attn_kernel(const unsigned char* __restrict__ qkv8,
                                                      const float* __restrict__ be,
                                                      __bf16* __restrict__ outt) {
  __shared__ __align__(16) char smem_all[4][16384];
  const int tid = threadIdx.x;
  const int lane = tid & 63;
  const int w = tid >> 6;
  char* sm = (char*)smem_all[w];
  const int pair = blockIdx.x * 4 + w;               // 6144 pairs
  const int h = pair % 6;
  const int wg = pair / 6;
  const int b = wg >> 4;
  const int wi = wg & 15;
  const int wh = wi >> 2, wwi = wi & 3;
  const int cc = lane & 15, g = lane >> 4;

  {
    int rsub = lane >> 2;                            // 0..15
    int G = lane & 3;
    #pragma unroll
    for (int it = 0; it < 4; ++it) {
      int r = it * 16 + rsub;
      int m = r < 49 ? r : 48;
      int im = div7u(m), jm = m - im * 7;
      int sh = wh * 7 + im + 3; if (sh >= 28) sh -= 28;
      int sw = wwi * 7 + jm + 3; if (sw >= 28) sw -= 28;
      size_t trow = (size_t)(b * 784 + sh * 28 + sw) * 1536;
      int srcG = (G ^ (r & 3)) << 4;
      __builtin_amdgcn_global_load_lds((const GAS void*)(qkv8 + trow + 384 + h * 64 + srcG),
                                       (LAS void*)(sm + it * 1024), 16, 0, 0);         // K
      __builtin_amdgcn_global_load_lds((const GAS void*)(qkv8 + trow + h * 64 + srcG),
                                       (LAS void*)(sm + 4096 + it * 1024), 16, 0, 0);  // Q
    }
  }
  asm volatile("s_waitcnt vmcnt(0)" ::: "memory");
  __syncthreads();

  f32x4 sacc[4][4] = {};
  #pragma unroll
  for (int ks = 0; ks < 2; ++ks) {
    long kf[4], qf[4];
    const int e = (ks << 2) + g;                     // 0..7
    #pragma unroll
    for (int mi = 0; mi < 4; ++mi) {
      int r = (mi << 4) + cc;
      int addr = (r << 6) + ((((e >> 1) ^ (r & 3)) << 4)) + ((e & 1) << 3);
      kf[mi] = *(const long*)(sm + addr);
    }
    #pragma unroll
    for (int nj = 0; nj < 4; ++nj) {
      int r = (nj << 4) + cc;
      int addr = (r << 6) + ((((e >> 1) ^ (r & 3)) << 4)) + ((e & 1) << 3);
      qf[nj] = *(const long*)(sm + 4096 + addr);
    }
    #pragma unroll
    for (int mi = 0; mi < 4; ++mi)
      #pragma unroll
      for (int nj = 0; nj < 4; ++nj)
        sacc[mi][nj] = __builtin_amdgcn_mfma_f32_16x16x32_fp8_fp8(kf[mi], qf[nj], sacc[mi][nj], 0, 0, 0);
  }
  __syncthreads();

  int r9m[4][4];
  #pragma unroll
  for (int mi = 0; mi < 4; ++mi)
    #pragma unroll
    for (int rr = 0; rr < 4; ++rr) {
      int m = (mi << 4) + (g << 2) + rr; if (m > 48) m = 48;
      int im = div7u(m), jm = m - im * 7;
      int sh = wh * 7 + im, sw = wwi * 7 + jm;
      r9m[mi][rr] = ((sh < 21) ? 0 : (sh < 25 ? 1 : 2)) * 3 + ((sw < 21) ? 0 : (sw < 25 ? 1 : 2));
    }

  #pragma unroll
  for (int nj = 0; nj < 4; ++nj) {
    int n = (nj << 4) + cc;
    int ncl = n > 48 ? 48 : n;
    int in_ = div7u(ncl), jn = ncl - in_ * 7;
    int shn = wh * 7 + in_, swn = wwi * 7 + jn;
    int r9n = ((shn < 21) ? 0 : (shn < 25 ? 1 : 2)) * 3 + ((swn < 21) ? 0 : (swn < 25 ? 1 : 2));
    float mx = -1e30f;
    #pragma unroll
    for (int mi = 0; mi < 4; ++mi) {
      f32x4 bia = *(const f32x4*)(be + (((h << 6) + n) << 6) + (mi << 4) + (g << 2));
      #pragma unroll
      for (int rr = 0; rr < 4; ++rr) {
        int m = (mi << 4) + (g << 2) + rr;
        float t = (m < 49)
            ? sacc[mi][nj][rr] * 0.125f + bia[rr] + ((r9m[mi][rr] == r9n) ? 0.f : -100.f)
            : -1e30f;
        sacc[mi][nj][rr] = t;
        mx = fmaxf(mx, t);
      }
    }
    mx = fmaxf(mx, __shfl_xor(mx, 16, 64));
    mx = fmaxf(mx, __shfl_xor(mx, 32, 64));
    float sum = 0.f;
    #pragma unroll
    for (int mi = 0; mi < 4; ++mi)
      #pragma unroll
      for (int rr = 0; rr < 4; ++rr) {
        float e = __expf(sacc[mi][nj][rr] - mx);
        sacc[mi][nj][rr] = e;
        sum += e;
      }
    sum += __shfl_xor(sum, 16, 64);
    sum += __shfl_xor(sum, 32, 64);
    float inv = __builtin_amdgcn_rcpf(sum);
    #pragma unroll
    for (int mi = 0; mi < 4; ++mi) {
      bf16x4 pk = {(__bf16)(sacc[mi][nj][0] * inv), (__bf16)(sacc[mi][nj][1] * inv),
                   (__bf16)(sacc[mi][nj][2] * inv), (__bf16)(sacc[mi][nj][3] * inv)};
      *(bf16x4*)(sm + 8192 + (n << 7) + (((mi << 5) + (g << 3)) ^ ((n & 7) << 4))) = pk;
    }
  }

  {
    int ml = lane & 15, dq = lane >> 4;
    #pragma unroll
    for (int it = 0; it < 4; ++it) {
      int m = (it << 4) + ml;
      int mc_ = m > 48 ? 48 : m;
      int im = div7u(mc_), jm = mc_ - im * 7;
      int sh = wh * 7 + im + 3; if (sh >= 28) sh -= 28;
      int sw = wwi * 7 + jm + 3; if (sw >= 28) sw -= 28;
      const __bf16* gv = (const __bf16*)(qkv8 + (size_t)(b * 784 + sh * 28 + sw) * 1536 + 768) + h * 64;
      #pragma unroll
      for (int hd = 0; hd < 2; ++hd) {
        int dbase = (hd << 5) + (dq << 3);
        bf16x8 v = *(const bf16x8*)(gv + dbase);
        #pragma unroll
        for (int j = 0; j < 8; ++j) {
          int d = dbase + j;
          *(__bf16*)(sm + (d << 7) + ((((m >> 3) ^ (d & 7)) << 4) + ((m & 7) << 1))) = v[j];
        }
      }
    }
  }
  __syncthreads();

  f32x4 oacc[4][4] = {};
  #pragma unroll
  for (int ks = 0; ks < 2; ++ks) {
    bf16x8 pf[4], vf[4];
    #pragma unroll
    for (int ni = 0; ni < 4; ++ni) {
      int n = (ni << 4) + cc;
      pf[ni] = *(const bf16x8*)(sm + 8192 + (n << 7) + (((ks << 6) + (g << 4)) ^ ((n & 7) << 4)));
    }
    #pragma unroll
    for (int dj = 0; dj < 4; ++dj) {
      int d = (dj << 4) + cc;
      vf[dj] = *(const bf16x8*)(sm + (d << 7) + ((((ks << 2) + g) ^ (d & 7)) << 4));
    }
    #pragma unroll
    for (int ni = 0; ni < 4; ++ni)
      #pragma unroll
      for (int dj = 0; dj < 4; ++dj)
        oacc[ni][dj] = __builtin_amdgcn_mfma_f32_16x16x32_bf16(pf[ni], vf[dj], oacc[ni][dj], 0, 0, 0);
  }

  #pragma unroll
  for (int ni = 0; ni < 4; ++ni)
    #pragma unroll
    for (int rr = 0; rr < 4; ++rr) {
      int n = (ni << 4) + (g << 2) + rr;
      if (n < 49) {
        int im = div7u(n), jn = n - im * 7;
        int sh = wh * 7 + im + 3; if (sh >= 28) sh -= 28;
        int sw = wwi * 7 + jn + 3; if (sw >= 28) sw -= 28;
        __bf16* op = outt + (size_t)(b * 784 + sh * 28 + sw) * 384 + h * 64;
        #pragma unroll
        for (int dj = 0; dj < 4; ++dj)
          op[(dj << 4) + cc] = (__bf16)oacc[ni][dj][rr];
      }
    }
}

// ---------------- host launcher ----------------
extern "C" void kernel_launch(void* const* d_in, const int* in_sizes, int n_in,
                              void* d_out, int out_size, void* d_ws, size_t ws_size,
                              hipStream_t stream) {
  (void)in_sizes; (void)n_in; (void)out_size; (void)ws_size;
  const float* x     = (const float*)d_in[0];
  const float* n1w   = (const float*)d_in[1];
  const float* n1b   = (const float*)d_in[2];
  const float* qkvw  = (const float*)d_in[3];
  const float* tbl   = (const float*)d_in[4];
  const float* projw = (const float*)d_in[5];
  const float* n2w   = (const float*)d_in[6];
  const float* n2b   = (const float*)d_in[7];
  const float* w1    = (const float*)d_in[8];
  const float* w3    = (const float*)d_in[9];
  float* out = (float*)d_out;

  char* ws = (char*)d_ws;
  __bf16* bufA = (__bf16*)ws;                               // 38,535,168 B
  unsigned char* h8 = (unsigned char*)(ws + 38535168);      // 77,070,336 B (qkv8 / h fp8)
  __bf16* x2b = (__bf16*)(ws + 38535168 + 77070336);        // 38,535,168 B (x2 bf16)
  float*  be   = (float*)(ws + 154140672);                  // 98,304 B
  __bf16* wq   = (__bf16*)(ws + 154238976);
  __bf16* wp   = wq + 442368;
  __bf16* wm1  = wp + 147456;
  unsigned char* w3f8 = (unsigned char*)(wm1 + 589824);     // 589,824 B fp8

  cvt_all_kernel<<<5856, 256, 0, stream>>>(qkvw, projw, w1, w3, wq, wp, wm1, w3f8, tbl, be);

  // LN1(x fp32) -> xn_t (bufA)
  ln_t_kernel<float><<<784, 256, 0, stream>>>(x, n1w, n1b, bufA);
  // qkv -> mixed-precision qkv8 [tok][1536B]: Q,K fp8 + V bf16
  gemm_bt<4><<<392 * 9, 256, 0, stream>>>(wq, 384, bufA, 384, 384, 9,
                                          (void*)h8, 1536, nullptr, nullptr);
  // attention -> attn_out_t (bufA)
  attn_kernel<<<1536, 256, 0, stream>>>(h8, be, bufA);
  // proj: attn_out @ Wp + x -> x2 bf16 channel-major (x2b)
  gemm_bt<3><<<392 * 3, 256, 0, stream>>>(wp, 384, bufA, 384, 384, 3,
                                          nullptr, 0, (void*)x2b, x);
  // LN2(x2 bf16) -> xn2_t (bufA)
  ln_t_kernel<__bf16><<<784, 256, 0, stream>>>(x2b, n2w, n2b, bufA);
  // mlp1: xn2 @ W1 -> gelu -> h fp8 (h8)
  gemm_bt<1><<<392 * 12, 256, 0, stream>>>(wm1, 384, bufA, 384, 384, 12,
                                           (void*)h8, 1536, nullptr, nullptr);
  // mlp2 (fp8 x fp8): h @ W3^T /8 + x2 -> final fp32 out
  gemm_f8<<<392 * 3, 256, 0, stream>>>(w3f8, h8, 3, out, x2b);
}